// Round 21
// baseline (3026.491 us; speedup 1.0000x reference)
//
#include <hip/hip_runtime.h>
#include <stdint.h>
#include <math.h>

#define NB 24
#define NC 128
#define NH 8
#define NDK 16
#define NL 512
#define NTOT (24*128*512)
#define GRIDN 384

typedef float f32x4 __attribute__((ext_vector_type(4)));
typedef short s16x4 __attribute__((ext_vector_type(4)));

__device__ inline f32x4 mfma_bf16_16x16x16(s16x4 a, s16x4 b, f32x4 c) {
#if defined(__HIP_DEVICE_COMPILE__)
#if __has_builtin(__builtin_amdgcn_mfma_f32_16x16x16bf16_1k)
  return __builtin_amdgcn_mfma_f32_16x16x16bf16_1k(a, b, c, 0, 0, 0);
#else
  return __builtin_amdgcn_mfma_f32_16x16x16_bf16(a, b, c, 0, 0, 0);
#endif
#else
  (void)a; (void)b;
  return c;
#endif
}

__device__ inline unsigned short f2bf(float x) {   // RNE float->bf16
  uint32_t u = __float_as_uint(x);
  return (unsigned short)((u + 0x7FFFu + ((u >> 16) & 1u)) >> 16);
}
__device__ inline float bf2f(unsigned short s) {
  return __uint_as_float(((uint32_t)s) << 16);
}

// ---------------- threefry2x32 (JAX-compatible) ----------------
__host__ __device__ inline void tf2x32(uint32_t k0, uint32_t k1, uint32_t& x0, uint32_t& x1) {
  uint32_t ks2 = k0 ^ k1 ^ 0x1BD11BDAu;
  x0 += k0; x1 += k1;
#define TF_R(r) { x0 += x1; x1 = (x1 << r) | (x1 >> (32 - r)); x1 ^= x0; }
  TF_R(13) TF_R(15) TF_R(26) TF_R(6)
  x0 += k1;  x1 += ks2 + 1u;
  TF_R(17) TF_R(29) TF_R(16) TF_R(24)
  x0 += ks2; x1 += k0 + 2u;
  TF_R(13) TF_R(15) TF_R(26) TF_R(6)
  x0 += k0;  x1 += k1 + 3u;
  TF_R(17) TF_R(29) TF_R(16) TF_R(24)
  x0 += k1;  x1 += ks2 + 4u;
  TF_R(13) TF_R(15) TF_R(26) TF_R(6)
  x0 += ks2; x1 += k0 + 5u;
#undef TF_R
}

__device__ inline float drop_scale(uint32_t k0, uint32_t k1, uint32_t idx) {
  uint32_t x0 = 0u, x1 = idx;
  tf2x32(k0, k1, x0, x1);
  uint32_t bits = x0 ^ x1;
  float u = __uint_as_float((bits >> 9) | 0x3f800000u) - 1.0f;
  return (u < 0.9f) ? (1.0f / 0.9f) : 0.0f;
}

// ---------------- weight split arena (ushort offsets) ----------------
#define S0 (4*128*128)
#define SW (24*128*128)
#define SQ (8*24*16*128)
#define oPwH 0
#define oPwL (S0)
#define oWoH (2*S0)
#define oWoL (2*S0 + SW)
#define oWH  (2*S0 + 2*SW)
#define oWL  (2*S0 + 3*SW)
#define oQH  (2*S0 + 4*SW)
#define oQL  (2*S0 + 4*SW + SQ)
#define oKH  (2*S0 + 4*SW + 2*SQ)
#define oKL  (2*S0 + 4*SW + 3*SQ)
#define oVH  (2*S0 + 4*SW + 4*SQ)
#define oVL  (2*S0 + 4*SW + 5*SQ)
#define PREP_TOT (S0 + 2*SW + 3*SQ)

// ---------------- shared-memory union (max 57600 B) ----------------
union SU {
  struct { unsigned short Ah[64][68], Al[64][68], Xh[64][68], Xl[64][68]; } g;  // 34816 B
  struct { float rb[4][520]; } n;                                               // 8320 B
  struct { unsigned short QtH[512][16], QtL[512][16],
           KtH[128][16], KtL[128][16], Vt[16][520]; } a;                        // 57600 B
};

// ---------------- grid barrier: monotonic counters + gen flag, per-thread fences ----------------
// bar[i*32], i=0..15: arrival sub-counters; bar[512]: generation flag. Zeroed per launch.
__device__ __forceinline__ void gbar(unsigned* bar, unsigned rnd, int bidx) {
  __threadfence();                 // EVERY thread releases its own writes (agent scope)
  __syncthreads();
  if (threadIdx.x == 0) {
    __hip_atomic_fetch_add(&bar[(bidx & 15) * 32], 1u,
                           __ATOMIC_RELEASE, __HIP_MEMORY_SCOPE_AGENT);
    if (bidx == 0) {
      unsigned target = rnd * (unsigned)GRIDN;
      for (;;) {
        unsigned s = 0;
#pragma unroll
        for (int i = 0; i < 16; ++i)
          s += __hip_atomic_load(&bar[i * 32], __ATOMIC_ACQUIRE, __HIP_MEMORY_SCOPE_AGENT);
        if (s >= target) break;
        __builtin_amdgcn_s_sleep(8);
      }
      __hip_atomic_store(&bar[512], rnd, __ATOMIC_RELEASE, __HIP_MEMORY_SCOPE_AGENT);
    } else {
      while (__hip_atomic_load(&bar[512], __ATOMIC_ACQUIRE, __HIP_MEMORY_SCOPE_AGENT) < rnd)
        __builtin_amdgcn_s_sleep(8);
    }
  }
  __syncthreads();
  __threadfence();                 // EVERY thread acquires (invalidate stale caches)
}

// ---------------- stage: layernorm (+ optional depthwise conv) -> bf16 hi/lo ----------------
template<bool DOCONV>
__device__ __forceinline__ void norm_stage(SU* su, const float* __restrict__ cur,
                                           unsigned short* __restrict__ oh,
                                           unsigned short* __restrict__ ol,
                                           const float* __restrict__ dww,
                                           const float* __restrict__ dwb,
                                           int bidx, int tid) {
  int wi = tid >> 6, lt = tid & 63;
  for (int r0 = bidx * 4; r0 < NB * NC; r0 += GRIDN * 4) {   // 2 iters per block
    int row = r0 + wi;
    int c = row & (NC - 1);
    const float* rp = cur + (size_t)row * NL;
    float4 v0 = ((const float4*)rp)[lt * 2];
    float4 v1 = ((const float4*)rp)[lt * 2 + 1];
    float xr[8] = {v0.x, v0.y, v0.z, v0.w, v1.x, v1.y, v1.z, v1.w};
    float s = 0.f;
#pragma unroll
    for (int j = 0; j < 8; ++j) s += xr[j];
#pragma unroll
    for (int off = 32; off >= 1; off >>= 1) s += __shfl_xor(s, off);
    float mean = s * (1.0f / 512.0f);
    float sq = 0.f;
#pragma unroll
    for (int j = 0; j < 8; ++j) { xr[j] -= mean; sq += xr[j] * xr[j]; }
#pragma unroll
    for (int off = 32; off >= 1; off >>= 1) sq += __shfl_xor(sq, off);
    float inv = 1.0f / (sqrtf(sq * (1.0f / 511.0f)) + 1e-6f);

    size_t obase = (size_t)row * NL + lt * 8;
    if (!DOCONV) {
#pragma unroll
      for (int j = 0; j < 8; ++j) {
        float o = xr[j] * inv;
        unsigned short hi = f2bf(o);
        oh[obase + j] = hi;
        ol[obase + j] = f2bf(o - bf2f(hi));
      }
    } else {
      __syncthreads();
      float* rb = su->n.rb[wi];
      if (lt < 3) { rb[lt] = 0.f; rb[NL + 3 + lt] = 0.f; }
#pragma unroll
      for (int j = 0; j < 8; ++j) rb[3 + lt * 8 + j] = xr[j] * inv;
      __syncthreads();
      float wv[7];
#pragma unroll
      for (int u = 0; u < 7; ++u) wv[u] = dww[c * 7 + u];
      float bias = dwb[c];
#pragma unroll
      for (int j = 0; j < 8; ++j) {
        int l = lt * 8 + j;
        float o = bias;
#pragma unroll
        for (int u = 0; u < 7; ++u) o = fmaf(rb[l + u], wv[u], o);
        unsigned short hi = f2bf(o);
        oh[obase + j] = hi;
        ol[obase + j] = f2bf(o - bf2f(hi));
      }
    }
  }
}

// ---------------- stage: MFMA GEMM unit (64x64 out), pre-split operands ----------------
template<int EPI, bool A_PER_B>   // EPI: 0 bias+relu+res+drop, 1 res+drop, 2 relu+res+drop
__device__ __forceinline__ void gemm_unit(SU* su, int unit,
    const unsigned short* __restrict__ AhB, const unsigned short* __restrict__ AlB,
    const unsigned short* __restrict__ XhB, const unsigned short* __restrict__ XlB,
    const float* __restrict__ bias, const float* __restrict__ resid,
    float* __restrict__ Yout, uint32_t k0, uint32_t k1, int tid) {
  int b  = unit >> 4;
  int m0 = ((unit >> 3) & 1) << 6;
  int l0 = (unit & 7) << 6;
  const int lane = tid & 63, w = tid >> 6;
  const int g = lane >> 4, j16 = lane & 15;
  const unsigned short* Abh = AhB + (A_PER_B ? (size_t)b * NC * NC : 0);
  const unsigned short* Abl = AlB + (A_PER_B ? (size_t)b * NC * NC : 0);
  const size_t xb = (size_t)b * NC * NL;

  f32x4 acc[4] = {{0.f,0.f,0.f,0.f},{0.f,0.f,0.f,0.f},{0.f,0.f,0.f,0.f},{0.f,0.f,0.f,0.f}};

  for (int kc = 0; kc < 2; ++kc) {
#pragma unroll
    for (int i = 0; i < 4; ++i) {
      int id = tid + i * 256;
      int r = id >> 4, uu = (id & 15) << 2;
      *(s16x4*)&su->g.Ah[r][uu] = *(const s16x4*)&Abh[(size_t)(m0 + r) * NC + kc * 64 + uu];
      *(s16x4*)&su->g.Al[r][uu] = *(const s16x4*)&Abl[(size_t)(m0 + r) * NC + kc * 64 + uu];
    }
    {
      int n = tid & 63, kq = (tid >> 6) * 16;
#pragma unroll
      for (int kk = 0; kk < 16; ++kk) {
        int k = kq + kk;
        size_t src = xb + (size_t)(kc * 64 + k) * NL + l0 + n;
        su->g.Xh[n][k] = XhB[src];
        su->g.Xl[n][k] = XlB[src];
      }
    }
    __syncthreads();
#pragma unroll
    for (int ks = 0; ks < 4; ++ks) {
      int ko = ks * 16 + 4 * g;
      s16x4 a_h = *(const s16x4*)&su->g.Ah[w * 16 + j16][ko];
      s16x4 a_l = *(const s16x4*)&su->g.Al[w * 16 + j16][ko];
#pragma unroll
      for (int nt = 0; nt < 4; ++nt) {
        s16x4 x_h = *(const s16x4*)&su->g.Xh[nt * 16 + j16][ko];
        s16x4 x_l = *(const s16x4*)&su->g.Xl[nt * 16 + j16][ko];
        acc[nt] = mfma_bf16_16x16x16(a_h, x_h, acc[nt]);
        acc[nt] = mfma_bf16_16x16x16(a_l, x_h, acc[nt]);
        acc[nt] = mfma_bf16_16x16x16(a_h, x_l, acc[nt]);
      }
    }
    __syncthreads();
  }

#pragma unroll
  for (int nt = 0; nt < 4; ++nt) {
    int n = l0 + nt * 16 + j16;
#pragma unroll
    for (int r = 0; r < 4; ++r) {
      int m = m0 + w * 16 + 4 * g + r;
      float val = acc[nt][r] + ((EPI == 0) ? bias[m] : 0.0f);
      if (EPI == 0 || EPI == 2) val = fmaxf(val, 0.0f);
      size_t idx = ((size_t)b * NC + m) * NL + n;
      float v2 = resid[idx] + val;
      float ds = drop_scale(k0, k1, (uint32_t)idx);
      Yout[idx] = (ds == 0.0f) ? 0.0f : (v2 / 0.9f);
    }
  }
}

// ---------------- stage: QKV projection unit ----------------
__device__ __forceinline__ void qkv_unit(SU* su, int unit,
    const unsigned short* __restrict__ wsp,
    const unsigned short* __restrict__ XhB, const unsigned short* __restrict__ XlB,
    unsigned short* __restrict__ qhw, unsigned short* __restrict__ qlw,
    unsigned short* __restrict__ khw, unsigned short* __restrict__ klw,
    unsigned short* __restrict__ vbw, int tid) {
  int b = unit / 48;
  int rem = unit - b * 48;
  int m0 = (rem >> 3) << 6;
  int l0 = (rem & 7) << 6;
  const int lane = tid & 63, w = tid >> 6;
  const int g = lane >> 4, j16 = lane & 15;
  const int sel = m0 >> 7;
  const unsigned short* WpH = wsp + ((sel == 0) ? oQH : (sel == 1) ? oKH : oVH);
  const unsigned short* WpL = wsp + ((sel == 0) ? oQL : (sel == 1) ? oKL : oVL);
  const size_t xb = (size_t)b * NC * NL;

  f32x4 acc[4] = {{0.f,0.f,0.f,0.f},{0.f,0.f,0.f,0.f},{0.f,0.f,0.f,0.f},{0.f,0.f,0.f,0.f}};

  for (int kc = 0; kc < 2; ++kc) {
#pragma unroll
    for (int i = 0; i < 4; ++i) {
      int id = tid + i * 256;
      int r = id >> 4, uu = (id & 15) << 2;
      int gr = m0 + r;
      int w_ = gr & 127, h = w_ >> 4, kk = w_ & 15;
      size_t rowoff = (((size_t)h * NB + b) * NDK + kk) * NC + kc * 64 + uu;
      *(s16x4*)&su->g.Ah[r][uu] = *(const s16x4*)&WpH[rowoff];
      *(s16x4*)&su->g.Al[r][uu] = *(const s16x4*)&WpL[rowoff];
    }
    {
      int n = tid & 63, kq = (tid >> 6) * 16;
#pragma unroll
      for (int kk = 0; kk < 16; ++kk) {
        int k = kq + kk;
        size_t src = xb + (size_t)(kc * 64 + k) * NL + l0 + n;
        su->g.Xh[n][k] = XhB[src];
        su->g.Xl[n][k] = XlB[src];
      }
    }
    __syncthreads();
#pragma unroll
    for (int ks = 0; ks < 4; ++ks) {
      int ko = ks * 16 + 4 * g;
      s16x4 a_h = *(const s16x4*)&su->g.Ah[w * 16 + j16][ko];
      s16x4 a_l = *(const s16x4*)&su->g.Al[w * 16 + j16][ko];
#pragma unroll
      for (int nt = 0; nt < 4; ++nt) {
        s16x4 x_h = *(const s16x4*)&su->g.Xh[nt * 16 + j16][ko];
        s16x4 x_l = *(const s16x4*)&su->g.Xl[nt * 16 + j16][ko];
        acc[nt] = mfma_bf16_16x16x16(a_h, x_h, acc[nt]);
        acc[nt] = mfma_bf16_16x16x16(a_l, x_h, acc[nt]);
        acc[nt] = mfma_bf16_16x16x16(a_h, x_l, acc[nt]);
      }
    }
    __syncthreads();
  }

#pragma unroll
  for (int nt = 0; nt < 4; ++nt) {
    int n = l0 + nt * 16 + j16;
#pragma unroll
    for (int r = 0; r < 4; ++r) {
      int grow = m0 + w * 16 + 4 * g + r;
      int w_ = grow & 127, h = w_ >> 4, kk = w_ & 15;
      size_t idx = (((size_t)h * NB + b) * NDK + kk) * NL + n;
      float v = acc[nt][r];
      if (sel == 0) {
        float sv = v * 0.25f;
        unsigned short hi = f2bf(sv);
        qhw[idx] = hi; qlw[idx] = f2bf(sv - bf2f(hi));
      } else if (sel == 1) {
        unsigned short hi = f2bf(v);
        khw[idx] = hi; klw[idx] = f2bf(v - bf2f(hi));
      } else {
        vbw[idx] = f2bf(v);
      }
    }
  }
}

// ---------------- stage: attention unit (fully LDS-resident) ----------------
__device__ __forceinline__ void attn_unit(SU* su, int unit,
    const unsigned short* __restrict__ qh, const unsigned short* __restrict__ ql,
    const unsigned short* __restrict__ kh, const unsigned short* __restrict__ kl,
    const unsigned short* __restrict__ vb,
    unsigned short* __restrict__ oh, unsigned short* __restrict__ ol, int tid) {
  const int lane = tid & 63, w = tid >> 6;
  const int g = lane >> 4, j16 = lane & 15;
  const int hb = unit >> 2, jq = unit & 3;     // unit in [0, 768)
  const int j0 = jq * 128;
  const int h = hb / NB, b = hb % NB;
  const size_t kb = (size_t)hb * NDK * NL;

  for (int n = 0; n < 32; ++n) {
    int e = n * 256 + tid;
    int k = e >> 9, i = e & 511;
    su->a.QtH[i][k] = qh[kb + (size_t)k * NL + i];
    su->a.QtL[i][k] = ql[kb + (size_t)k * NL + i];
  }
  for (int n = 0; n < 16; ++n) {
    int e = n * 256 + tid;
    int v = e >> 8, i2 = e & 255;
    *(uint32_t*)&su->a.Vt[v][i2 * 2] = *(const uint32_t*)&vb[kb + (size_t)v * NL + i2 * 2];
  }
  for (int n = 0; n < 8; ++n) {
    int e = n * 256 + tid;
    int k = e >> 7, j = e & 127;
    su->a.KtH[j][k] = kh[kb + (size_t)k * NL + j0 + j];
    su->a.KtL[j][k] = kl[kb + (size_t)k * NL + j0 + j];
  }
  __syncthreads();

  s16x4 KhiF[2], KloF[2];
#pragma unroll
  for (int q = 0; q < 2; ++q) {
    int jj = (w * 2 + q) * 16 + j16;
    KhiF[q] = *(const s16x4*)&su->a.KtH[jj][4 * g];
    KloF[q] = *(const s16x4*)&su->a.KtL[jj][4 * g];
  }

  float Mq[2] = {-INFINITY, -INFINITY};
  float lq[2] = {0.f, 0.f};
  f32x4 hC[2] = {{0.f, 0.f, 0.f, 0.f}, {0.f, 0.f, 0.f, 0.f}};

  for (int it = 0; it < 32; ++it) {
    s16x4 Qhi = *(const s16x4*)&su->a.QtH[it * 16 + j16][4 * g];
    s16x4 Qlo = *(const s16x4*)&su->a.QtL[it * 16 + j16][4 * g];
    s16x4 Vf  = *(const s16x4*)&su->a.Vt[j16][it * 16 + 4 * g];
#pragma unroll
    for (int q = 0; q < 2; ++q) {
      f32x4 S = {0.f, 0.f, 0.f, 0.f};
      S = mfma_bf16_16x16x16(Qhi, KhiF[q], S);
      S = mfma_bf16_16x16x16(Qlo, KhiF[q], S);
      S = mfma_bf16_16x16x16(Qhi, KloF[q], S);
      float tm = fmaxf(fmaxf(S[0], S[1]), fmaxf(S[2], S[3]));
      tm = fmaxf(tm, __shfl_xor(tm, 16));
      tm = fmaxf(tm, __shfl_xor(tm, 32));
      float Mn = fmaxf(Mq[q], tm);
      float corr = __expf(Mq[q] - Mn);
      Mq[q] = Mn;
      float p0 = __expf(S[0] - Mn), p1 = __expf(S[1] - Mn);
      float p2 = __expf(S[2] - Mn), p3 = __expf(S[3] - Mn);
      lq[q] = lq[q] * corr + ((p0 + p1) + (p2 + p3));
      hC[q] = hC[q] * corr;
      union { uint32_t u[2]; s16x4 s; } bp;
      bp.u[0] = (uint32_t)f2bf(p0) | ((uint32_t)f2bf(p1) << 16);
      bp.u[1] = (uint32_t)f2bf(p2) | ((uint32_t)f2bf(p3) << 16);
      hC[q] = mfma_bf16_16x16x16(Vf, bp.s, hC[q]);
    }
  }

#pragma unroll
  for (int q = 0; q < 2; ++q) {
    float l2 = lq[q] + __shfl_xor(lq[q], 16);
    float L  = l2 + __shfl_xor(l2, 32);
    float invL = 1.0f / L;
    int jglob = j0 + (w * 2 + q) * 16 + j16;
#pragma unroll
    for (int r = 0; r < 4; ++r) {
      float val = hC[q][r] * invL;
      size_t idx = ((size_t)b * NC + h * NDK + 4 * g + r) * NL + jglob;
      unsigned short hi = f2bf(val);
      oh[idx] = hi;
      ol[idx] = f2bf(val - bf2f(hi));
    }
  }
}

// ---------------- the persistent mega-kernel ----------------
__global__ __launch_bounds__(256, 2) void mega_kernel(
    const float* __restrict__ x,
    const float* __restrict__ dw_w, const float* __restrict__ dw_b,
    const float* __restrict__ pw_w, const float* __restrict__ pw_b,
    const float* __restrict__ Wq, const float* __restrict__ Wk,
    const float* __restrict__ Wv, const float* __restrict__ Wo,
    const float* __restrict__ W, float* __restrict__ out,
    unsigned* bar, float* cur,
    unsigned short* XhB, unsigned short* XlB,
    unsigned short* qh, unsigned short* ql,
    unsigned short* kh, unsigned short* kl, unsigned short* vb,
    unsigned short* wsp,
    uint32_t ka0, uint32_t kb0, uint32_t ka1, uint32_t kb1,
    uint32_t ka2, uint32_t kb2, uint32_t ka3, uint32_t kb3,
    uint32_t ka4, uint32_t kb4, uint32_t ka5, uint32_t kb5) {
  __shared__ SU su;
  const int bidx = blockIdx.x, tid = threadIdx.x;
  const uint32_t FA[6] = {ka0, ka1, ka2, ka3, ka4, ka5};
  const uint32_t FB[6] = {kb0, kb1, kb2, kb3, kb4, kb5};
  unsigned rnd = 0;

  // ---- S0: weight hi/lo prep + pos-enc ----
  for (int idx = bidx * 256 + tid; idx < PREP_TOT; idx += GRIDN * 256) {
    const float* src; unsigned short *dh, *dl; int off;
    if (idx < S0)                { src = pw_w; dh = wsp + oPwH; dl = wsp + oPwL; off = idx; }
    else if (idx < S0 + SW)      { src = Wo;   dh = wsp + oWoH; dl = wsp + oWoL; off = idx - S0; }
    else if (idx < S0 + 2*SW)    { src = W;    dh = wsp + oWH;  dl = wsp + oWL;  off = idx - S0 - SW; }
    else if (idx < S0 + 2*SW + SQ)   { src = Wq; dh = wsp + oQH; dl = wsp + oQL; off = idx - S0 - 2*SW; }
    else if (idx < S0 + 2*SW + 2*SQ) { src = Wk; dh = wsp + oKH; dl = wsp + oKL; off = idx - S0 - 2*SW - SQ; }
    else                             { src = Wv; dh = wsp + oVH; dl = wsp + oVL; off = idx - S0 - 2*SW - 2*SQ; }
    float v = src[off];
    unsigned short hi = f2bf(v);
    dh[off] = hi;
    dl[off] = f2bf(v - bf2f(hi));
  }
  {
    int e0 = bidx * 256 + tid;
    int l = e0 & 511;
    int c0 = (e0 >> 9) & 127;
    float peA, peB;
    {
      int ce = c0 & ~1;
      double base = exp(-(double)ce * 9.210340371976184 / 128.0);
      float freq = (c0 & 1) ? -(float)base : (float)base;
      float phase = (c0 & 1) ? (float)(M_PI / 2.0) : 0.0f;
      peA = sinf(sinf((float)l * freq + phase));
    }
    {
      int c1 = (c0 + 64) & 127;
      int ce = c1 & ~1;
      double base = exp(-(double)ce * 9.210340371976184 / 128.0);
      float freq = (c1 & 1) ? -(float)base : (float)base;
      float phase = (c1 & 1) ? (float)(M_PI / 2.0) : 0.0f;
      peB = sinf(sinf((float)l * freq + phase));
    }
    int p = 0;
    for (int e = e0; e < NTOT; e += GRIDN * 256, p ^= 1)
      cur[e] = x[e] + (p ? peB : peA);
  }
  gbar(bar, ++rnd, bidx);

  // ---- 4 conv blocks ----
#pragma unroll 1
  for (int ci = 0; ci < 4; ++ci) {
    norm_stage<true>(&su, cur, XhB, XlB, dw_w + ci * NC * 7, dw_b + ci * NC, bidx, tid);
    gbar(bar, ++rnd, bidx);
    gemm_unit<0, false>(&su, bidx, wsp + oPwH + ci * NC * NC, wsp + oPwL + ci * NC * NC,
                        XhB, XlB, pw_b + ci * NC, cur, cur, FA[ci], FB[ci], tid);
    gbar(bar, ++rnd, bidx);
  }

  // ---- attention ----
  norm_stage<false>(&su, cur, XhB, XlB, nullptr, nullptr, bidx, tid);
  gbar(bar, ++rnd, bidx);
  for (int unit = bidx; unit < 1152; unit += GRIDN)
    qkv_unit(&su, unit, wsp, XhB, XlB, qh, ql, kh, kl, vb, tid);
  gbar(bar, ++rnd, bidx);
  for (int unit = bidx; unit < 768; unit += GRIDN)   // FIXED: 768 units (192 hb x 4 jq)
    attn_unit(&su, unit, qh, ql, kh, kl, vb, XhB, XlB, tid);
  gbar(bar, ++rnd, bidx);
  gemm_unit<1, true>(&su, bidx, wsp + oWoH, wsp + oWoL, XhB, XlB,
                     nullptr, cur, cur, FA[4], FB[4], tid);
  gbar(bar, ++rnd, bidx);

  // ---- final projection ----
  norm_stage<false>(&su, cur, XhB, XlB, nullptr, nullptr, bidx, tid);
  gbar(bar, ++rnd, bidx);
  gemm_unit<2, true>(&su, bidx, wsp + oWH, wsp + oWL, XhB, XlB,
                     nullptr, cur, out, FA[5], FB[5], tid);
}

__global__ void zero_bar_kernel(unsigned* bar) {
  bar[threadIdx.x] = 0u;
}

// ---------------- launch ----------------
extern "C" void kernel_launch(void* const* d_in, const int* in_sizes, int n_in,
                              void* d_out, int out_size, void* d_ws, size_t ws_size,
                              hipStream_t stream) {
  (void)in_sizes; (void)n_in; (void)out_size; (void)ws_size;
  const float* x    = (const float*)d_in[0];
  const float* dw_w = (const float*)d_in[1];
  const float* dw_b = (const float*)d_in[2];
  const float* pw_w = (const float*)d_in[3];
  const float* pw_b = (const float*)d_in[4];
  const float* Wq   = (const float*)d_in[5];
  const float* Wk   = (const float*)d_in[6];
  const float* Wv   = (const float*)d_in[7];
  const float* Wo   = (const float*)d_in[8];
  const float* W    = (const float*)d_in[9];
  float* out = (float*)d_out;

  const size_t N = NTOT;
  unsigned* bar = (unsigned*)d_ws;                       // 1024 uints (4 KB)
  float* cur = (float*)((char*)d_ws + 4096);
  unsigned short* XhB = (unsigned short*)(cur + N);
  unsigned short* XlB = XhB + N;
  unsigned short* qh  = XlB + N;
  unsigned short* ql  = qh + N;
  unsigned short* kh  = ql + N;
  unsigned short* kl  = kh + N;
  unsigned short* vb  = kl + N;
  unsigned short* wsp = vb + N;

  uint32_t fk0[6], fk1[6];
  for (int i = 0; i < 6; ++i) {
    uint32_t a = 0u, bb = (uint32_t)i;
    tf2x32(0u, 7u, a, bb);
    fk0[i] = a; fk1[i] = bb;
  }

  zero_bar_kernel<<<1, 1024, 0, stream>>>(bar);
  mega_kernel<<<GRIDN, 256, 0, stream>>>(
      x, dw_w, dw_b, pw_w, pw_b, Wq, Wk, Wv, Wo, W, out,
      bar, cur, XhB, XlB, qh, ql, kh, kl, vb, wsp,
      fk0[0], fk1[0], fk0[1], fk1[1], fk0[2], fk1[2],
      fk0[3], fk1[3], fk0[4], fk1[4], fk0[5], fk1[5]);
}